// Round 1
// baseline (14085.663 us; speedup 1.0000x reference)
//
#include <hip/hip_runtime.h>

#define HB 64      // batch
#define HT 1024    // time
#define HI 256     // input dim
#define HH 512     // hidden dim

typedef short short8 __attribute__((ext_vector_type(8)));
typedef float f32x4 __attribute__((ext_vector_type(4)));

__device__ __forceinline__ unsigned short f2bf(float f) {
    unsigned u = __float_as_uint(f);
    u += 0x7FFF + ((u >> 16) & 1);          // round-to-nearest-even
    return (unsigned short)(u >> 16);
}

__device__ __forceinline__ float sigmoidf_(float x) {
    return 1.0f / (1.0f + __expf(-x));
}

// ---------------------------------------------------------------------------
// Pack weights to bf16 in MFMA B-fragment-linear layout.
// Wcat0 = [W_ih0 (2048x256) | W_hh0 (2048x512)]  -> K0 = 768, 24 k-tiles
// Wcat1 = [W_ih1 (2048x512) | W_hh1 (2048x512)]  -> K1 = 1024, 32 k-tiles
// Layout: [nt(128)][kt][lane(64)][j(8)], element = W[nt*16+(l&15)][kt*32+(l>>4)*8+j]
// Also bias sums bs[layer][n] = b_ih[n] + b_hh[n].
// ---------------------------------------------------------------------------
__global__ void pack_weights(const float* __restrict__ Wih0, const float* __restrict__ Whh0,
                             const float* __restrict__ bih0, const float* __restrict__ bhh0,
                             const float* __restrict__ Wih1, const float* __restrict__ Whh1,
                             const float* __restrict__ bih1, const float* __restrict__ bhh1,
                             unsigned short* __restrict__ wp0,
                             unsigned short* __restrict__ wp1,
                             float* __restrict__ bs) {
    int idx = blockIdx.x * 256 + threadIdx.x;
    int stride = gridDim.x * 256;
    const int NP0 = 128 * 24 * 512;
    const int NP1 = 128 * 32 * 512;
    for (int e = idx; e < NP0; e += stride) {
        int j = e & 7, l = (e >> 3) & 63, rem = e >> 9;
        int kt = rem % 24, nt = rem / 24;
        int n = nt * 16 + (l & 15);
        int k = kt * 32 + ((l >> 4) << 3) + j;
        float v = (k < HI) ? Wih0[n * HI + k] : Whh0[n * HH + (k - HI)];
        wp0[e] = f2bf(v);
    }
    for (int e = idx; e < NP1; e += stride) {
        int j = e & 7, l = (e >> 3) & 63, rem = e >> 9;
        int kt = rem & 31, nt = rem >> 5;
        int n = nt * 16 + (l & 15);
        int k = kt * 32 + ((l >> 4) << 3) + j;
        float v = (k < HH) ? Wih1[n * HH + k] : Whh1[n * HH + (k - HH)];
        wp1[e] = f2bf(v);
    }
    for (int e = idx; e < 2048; e += stride) {
        bs[e]        = bih0[e] + bhh0[e];
        bs[2048 + e] = bih1[e] + bhh1[e];
    }
}

// ---------------------------------------------------------------------------
// Pack x (B,1,I,T) -> bf16 A-fragment layout xp[t][bt(4)][kt(8)][lane(64)][j(8)]
// element = x[b = bt*16+(l&15)][i = kt*32+(l>>4)*8+j][t]
// Block: (tt, ii, bt) handles t-tile of 16, i-tile of 32, b-tile of 16.
// ---------------------------------------------------------------------------
__global__ void pack_x(const float* __restrict__ x, unsigned short* __restrict__ xp) {
    int tt = blockIdx.x;   // 64
    int ii = blockIdx.y;   // 8
    int bt = blockIdx.z;   // 4
    int w  = threadIdx.x;  // 256
    __shared__ unsigned short tile[512][16];  // [m*32+iloc][tloc], 16 KB
    int tloc = w & 15;
    for (int q = 0; q < 32; ++q) {
        int p = q * 16 + (w >> 4);
        int m = p >> 5, iloc = p & 31;
        int b = bt * 16 + m, i = ii * 32 + iloc, t = tt * 16 + tloc;
        tile[p][tloc] = f2bf(x[((size_t)b * HI + i) * HT + t]);
    }
    __syncthreads();
    int e  = w * 2;
    int l  = e >> 3, j0 = e & 7;
    int m  = l & 15;
    int i0 = ((l >> 4) << 3) + j0;
    for (int ti = 0; ti < 16; ++ti) {
        int t = tt * 16 + ti;
        size_t base = ((size_t)(t * 4 + bt) * 8 + ii) * 512;
        unsigned v0 = tile[m * 32 + i0][ti];
        unsigned v1 = tile[m * 32 + i0 + 1][ti];
        ((unsigned int*)xp)[(base + e) >> 1] = v0 | (v1 << 16);
    }
}

__global__ void init_zero(float* __restrict__ z, int n) {
    int idx = blockIdx.x * 256 + threadIdx.x;
    for (int e = idx; e < n; e += gridDim.x * 256) z[e] = 0.0f;
}

// ---------------------------------------------------------------------------
// One pipelined LSTM step. Blocks 0..127: layer 0 at t=it. Blocks 128..255:
// layer 1 at t=it-1 (consumes h0 written by the PREVIOUS launch -> no
// intra-launch dependency). Each 1-wave block owns a 16-batch x 16-unit tile
// and computes all four gates (i,f,g,o) via MFMA.
// h rings: h0ring/h1ring are [2 slots][bt(4)][kt(16)][lane(64)][j(8)] bf16
// (A-fragment layout over K=H=512). Read slot and write slot differ per
// launch parity, so there is never a same-launch read/write race.
// ---------------------------------------------------------------------------
__global__ void __launch_bounds__(64) lstm_step(
        const unsigned short* __restrict__ wp0,
        const unsigned short* __restrict__ wp1,
        const float* __restrict__ bs,
        const unsigned short* __restrict__ xp,
        unsigned short* __restrict__ h0ring,
        unsigned short* __restrict__ h1ring,
        float* __restrict__ Cst,    // [2][64][512]
        float* __restrict__ Hst,    // [2][64][512]
        float* __restrict__ out,    // [64][1024][512]
        int it) {
    int bid = blockIdx.x;
    int layer = bid >> 7;
    int lbid = bid & 127;
    int mt = lbid & 3;        // batch tile (4 x 16)
    int ut = lbid >> 2;       // unit tile (32 x 16)
    int l = threadIdx.x;

    if (layer == 0) { if (it >= HT) return; }
    else            { if (it < 1)   return; }
    int t = (layer == 0) ? it : it - 1;

    int ul = l & 15, q = l >> 4;

    f32x4 acc[4];
    #pragma unroll
    for (int g = 0; g < 4; ++g) {
        float bv = bs[layer * 2048 + g * HH + ut * 16 + ul];
        f32x4 a; a[0] = bv; a[1] = bv; a[2] = bv; a[3] = bv;
        acc[g] = a;
    }

    // A-operand fragment pointers (short8-granular)
    const short8* h0rd = (const short8*)h0ring + ((size_t)(it & 1) * 4 + mt) * 16 * 64;

    if (layer == 0) {
        const short8* xa = (const short8*)xp + ((size_t)t * 4 + mt) * 8 * 64;
        const short8* Wb = (const short8*)wp0 + (size_t)ut * 24 * 64 + l;
        #pragma unroll
        for (int kt = 0; kt < 8; ++kt) {       // x part, K = 256
            short8 a = xa[kt * 64 + l];
            #pragma unroll
            for (int g = 0; g < 4; ++g) {
                short8 b = Wb[((size_t)g * 32 * 24 + kt) * 64];
                acc[g] = __builtin_amdgcn_mfma_f32_16x16x32_bf16(a, b, acc[g], 0, 0, 0);
            }
        }
        #pragma unroll
        for (int kt = 0; kt < 16; ++kt) {      // h part, K = 512
            short8 a = h0rd[kt * 64 + l];
            #pragma unroll
            for (int g = 0; g < 4; ++g) {
                short8 b = Wb[((size_t)g * 32 * 24 + 8 + kt) * 64];
                acc[g] = __builtin_amdgcn_mfma_f32_16x16x32_bf16(a, b, acc[g], 0, 0, 0);
            }
        }
    } else {
        const short8* h1rd = (const short8*)h1ring + ((size_t)((it + 1) & 1) * 4 + mt) * 16 * 64;
        const short8* Wb = (const short8*)wp1 + (size_t)ut * 32 * 64 + l;
        #pragma unroll
        for (int kt = 0; kt < 16; ++kt) {      // input = h0(t), K = 512
            short8 a = h0rd[kt * 64 + l];
            #pragma unroll
            for (int g = 0; g < 4; ++g) {
                short8 b = Wb[((size_t)g * 32 * 32 + kt) * 64];
                acc[g] = __builtin_amdgcn_mfma_f32_16x16x32_bf16(a, b, acc[g], 0, 0, 0);
            }
        }
        #pragma unroll
        for (int kt = 0; kt < 16; ++kt) {      // recurrent h1, K = 512
            short8 a = h1rd[kt * 64 + l];
            #pragma unroll
            for (int g = 0; g < 4; ++g) {
                short8 b = Wb[((size_t)g * 32 * 32 + 16 + kt) * 64];
                acc[g] = __builtin_amdgcn_mfma_f32_16x16x32_bf16(a, b, acc[g], 0, 0, 0);
            }
        }
    }

    // Epilogue: activations, cell update, h write-back (A-frag layout).
    int u = ut * 16 + ul;
    unsigned short* hw;
    size_t hwbase;
    if (layer == 0) {
        hw = h0ring;
        hwbase = ((size_t)(((it + 1) & 1) * 4 + mt) * 16 + (u >> 5)) * 512 + (u & 7);
    } else {
        hw = h1ring;
        hwbase = ((size_t)((it & 1) * 4 + mt) * 16 + (u >> 5)) * 512 + (u & 7);
    }
    int la_off = ((u >> 3) & 3) << 4;

    #pragma unroll
    for (int r = 0; r < 4; ++r) {
        int m = q * 4 + r;
        int b = mt * 16 + m;
        float iv = sigmoidf_(acc[0][r]);
        float fv = sigmoidf_(acc[1][r]);
        float gv = tanhf(acc[2][r]);
        float ov = sigmoidf_(acc[3][r]);
        size_t cidx = ((size_t)layer * HB + b) * HH + u;
        float c = fv * Cst[cidx] + iv * gv;
        Cst[cidx] = c;
        float h = ov * tanhf(c);
        Hst[cidx] = h;
        hw[hwbase + (size_t)(m + la_off) * 8] = f2bf(h);
        if (layer == 1) out[((size_t)b * HT + t) * HH + u] = h;
    }
}

// hidden = Hst (2,64,512), cell = Cst (2,64,512), appended after out.
__global__ void finalize(const float* __restrict__ Hst, const float* __restrict__ Cst,
                         float* __restrict__ out) {
    int idx = blockIdx.x * 256 + threadIdx.x;
    if (idx < 2 * HB * HH) {
        out[33554432 + idx]  = Hst[idx];
        out[33619968 + idx]  = Cst[idx];
    }
}

extern "C" void kernel_launch(void* const* d_in, const int* in_sizes, int n_in,
                              void* d_out, int out_size, void* d_ws, size_t ws_size,
                              hipStream_t stream) {
    const float* x    = (const float*)d_in[0];
    const float* Wih0 = (const float*)d_in[1];
    const float* Whh0 = (const float*)d_in[2];
    const float* bih0 = (const float*)d_in[3];
    const float* bhh0 = (const float*)d_in[4];
    const float* Wih1 = (const float*)d_in[5];
    const float* Whh1 = (const float*)d_in[6];
    const float* bih1 = (const float*)d_in[7];
    const float* bhh1 = (const float*)d_in[8];

    char* ws = (char*)d_ws;
    // ws layout (bytes):
    //   wp0:    0         .. 3,145,728   (128*24*512 bf16)
    //   wp1:    3,145,728 .. 7,340,032   (128*32*512 bf16)
    //   bs:     7,340,032 .. 7,356,416   (4096 f32)
    //   xp:     7,356,416 .. 40,910,848  (1024*4*8*512 bf16)
    //   zeroed: 40,910,848 .. 41,697,280 (h0ring 128KB | h1ring 128KB | Cst 256KB | Hst 256KB)
    unsigned short* wp0 = (unsigned short*)(ws + 0);
    unsigned short* wp1 = (unsigned short*)(ws + 3145728);
    float*          bsv = (float*)(ws + 7340032);
    unsigned short* xp  = (unsigned short*)(ws + 7356416);
    char* zbase = ws + 40910848;
    unsigned short* h0ring = (unsigned short*)zbase;
    unsigned short* h1ring = h0ring + 65536;
    float* Cst = (float*)(zbase + 262144);
    float* Hst = Cst + 65536;
    float* out = (float*)d_out;

    pack_weights<<<2048, 256, 0, stream>>>(Wih0, Whh0, bih0, bhh0,
                                           Wih1, Whh1, bih1, bhh1, wp0, wp1, bsv);
    pack_x<<<dim3(64, 8, 4), 256, 0, stream>>>(x, xp);
    init_zero<<<768, 256, 0, stream>>>((float*)zbase, 196608);

    for (int it = 0; it <= HT; ++it) {
        lstm_step<<<256, 64, 0, stream>>>(wp0, wp1, bsv, xp, h0ring, h1ring,
                                          Cst, Hst, out, it);
    }
    finalize<<<256, 256, 0, stream>>>(Hst, Cst, out);
}